// Round 2
// baseline (11114.546 us; speedup 1.0000x reference)
//
#include <hip/hip_runtime.h>
#include <stdint.h>

#define TT 128
#define NWG 256

typedef __attribute__((ext_vector_type(8))) short short8;
typedef __attribute__((ext_vector_type(4))) float f32x4;

__device__ __forceinline__ float blo(uint32_t u){ union{uint32_t i; float f;} v; v.i = u << 16; return v.f; }
__device__ __forceinline__ float bhi(uint32_t u){ union{uint32_t i; float f;} v; v.i = u & 0xffff0000u; return v.f; }
__device__ __forceinline__ float bf2f(uint16_t u){ union{uint32_t i; float f;} v; v.i = ((uint32_t)u) << 16; return v.f; }
__device__ __forceinline__ uint16_t f2bf(float f){
  union{float f; uint32_t i;} v; v.f = f;
  uint32_t r = v.i + 0x7fffu + ((v.i >> 16) & 1u);
  return (uint16_t)(r >> 16);
}

// ---------------- prep kernels ----------------
// memT2[b][e2][k] and mem2[b][k][e2], both packing (bf16(mem[b][k][2e2]), bf16(mem[b][k][2e2+1])) in a u32.
__global__ __launch_bounds__(256) void k_prep_mem(const float* __restrict__ mem,
                                                  uint32_t* __restrict__ memT2,
                                                  uint32_t* __restrict__ mem2) {
  int idx = blockIdx.x * 256 + threadIdx.x;   // 2 * 32*256*256
  if (idx < 2097152) {
    int k = idx & 255, e2 = (idx >> 8) & 255, b = idx >> 16;
    const float* p = mem + ((size_t)(b * 256 + k)) * 512 + e2 * 2;
    memT2[idx] = (uint32_t)f2bf(p[0]) | ((uint32_t)f2bf(p[1]) << 16);
  } else {
    int j = idx - 2097152;
    int e2 = j & 255, k = (j >> 8) & 255, b = j >> 16;
    const float* p = mem + ((size_t)(b * 256 + k)) * 512 + e2 * 2;
    mem2[j] = (uint32_t)f2bf(p[0]) | ((uint32_t)f2bf(p[1]) << 16);
  }
}

// Permuted+concatenated gate weights: row jp = wq*8 + q*2 + rr  ->  orig gate row oj = q*512 + wq*2 + rr.
// Wp[jp][k] = k<512 ? W_ih[oj][k] (context part) : W_hh[oj][k-512].  Wxp[jp][k] = W_ih[oj][512+k] (x part).
__global__ __launch_bounds__(256) void k_prep_w(const float* __restrict__ W_ih, const float* __restrict__ W_hh,
                                                const float* __restrict__ b_ih, const float* __restrict__ b_hh,
                                                uint16_t* __restrict__ Wp, uint16_t* __restrict__ Wxp,
                                                float* __restrict__ bias_perm) {
  int idx = blockIdx.x * 256 + threadIdx.x;   // 2048*1024
  int k = idx & 1023, jp = idx >> 10;
  int wq = jp >> 3, q = (jp >> 1) & 3, rr = jp & 1;
  int oj = q * 512 + wq * 2 + rr;
  float v = (k < 512) ? W_ih[(size_t)oj * 1024 + k] : W_hh[(size_t)oj * 512 + (k - 512)];
  Wp[idx] = f2bf(v);
  if (k < 512) Wxp[(size_t)jp * 512 + k] = f2bf(W_ih[(size_t)oj * 1024 + 512 + k]);
  if (k == 0) bias_perm[jp] = b_ih[oj] + b_hh[oj];
}

__global__ __launch_bounds__(256) void k_prep_wo(const float* __restrict__ W_out, uint16_t* __restrict__ WoP) {
  int idx = blockIdx.x * 256 + threadIdx.x;   // 10112*512 (pad rows zeroed)
  if (idx < 5120000) WoP[idx] = f2bf(W_out[idx]);
  else WoP[idx] = 0;
}

__global__ __launch_bounds__(256) void k_gather_x(const float* __restrict__ emb, const int* __restrict__ tgt,
                                                  uint16_t* __restrict__ Axg) {
  int idx = blockIdx.x * 256 + threadIdx.x;   // 4096*512
  int k = idx & 511, m = idx >> 9;
  Axg[idx] = f2bf(emb[(size_t)tgt[m] * 512 + k]);
}

// ---------------- bf16 MFMA GEMM, C = A(MxK) * B(NxK)^T + bias ----------------
// MODE 0: fp32 out row-major (logits, mask gcol<Nreal). MODE 1: bf16 out remapped rows (t*32+b) (Xg).
template<int MODE>
__global__ __launch_bounds__(256) void gemm_bt(const uint16_t* __restrict__ A, const uint16_t* __restrict__ B,
                                               const float* __restrict__ bias, void* __restrict__ Cout,
                                               int K, int Nreal, int ldc, int tilesN) {
  __shared__ __align__(16) uint16_t As[128 * 32];
  __shared__ __align__(16) uint16_t Bs[128 * 32];
  const int tid = threadIdx.x;
  const int wv = tid >> 6, lane = tid & 63;
  const int tm = blockIdx.x / tilesN, tn = blockIdx.x % tilesN;
  const int wr = wv >> 1, wc = wv & 1;

  f32x4 acc[4][4];
#pragma unroll
  for (int m = 0; m < 4; ++m)
#pragma unroll
    for (int n = 0; n < 4; ++n) acc[m][n] = (f32x4){0.f, 0.f, 0.f, 0.f};

  const int frow = lane & 15;
  const int fk = (lane >> 4) << 3;
  const int srow = lane >> 2;
  const int skof = (lane & 3) << 3;

  const uint16_t* Abase = A + (size_t)tm * 128 * K;
  const uint16_t* Bbase = B + (size_t)tn * 128 * K;

  for (int k0 = 0; k0 < K; k0 += 32) {
    __syncthreads();
#pragma unroll
    for (int i = 0; i < 2; ++i) {               // FIX: 8 chunks of 16 rows = 128 rows (was 16 chunks -> LDS overflow)
      const int chunk = wv * 2 + i;
      const int row = chunk * 16 + srow;
      const uint16_t* ga = Abase + (size_t)row * K + k0 + skof;
      const uint16_t* gb = Bbase + (size_t)row * K + k0 + skof;
      __builtin_amdgcn_global_load_lds((const __attribute__((address_space(1))) uint32_t*)(const void*)ga,
                                       (__attribute__((address_space(3))) uint32_t*)(void*)(As + chunk * 512),
                                       16, 0, 0);
      __builtin_amdgcn_global_load_lds((const __attribute__((address_space(1))) uint32_t*)(const void*)gb,
                                       (__attribute__((address_space(3))) uint32_t*)(void*)(Bs + chunk * 512),
                                       16, 0, 0);
    }
    __syncthreads();
    short8 af[4], bfr[4];
#pragma unroll
    for (int m = 0; m < 4; ++m) af[m] = *(const short8*)(As + (wr * 64 + m * 16 + frow) * 32 + fk);
#pragma unroll
    for (int n = 0; n < 4; ++n) bfr[n] = *(const short8*)(Bs + (wc * 64 + n * 16 + frow) * 32 + fk);
#pragma unroll
    for (int m = 0; m < 4; ++m)
#pragma unroll
      for (int n = 0; n < 4; ++n)
        acc[m][n] = __builtin_amdgcn_mfma_f32_16x16x32_bf16(af[m], bfr[n], acc[m][n], 0, 0, 0);
  }

  const int crow = (lane >> 4) << 2;
  const int ccol = lane & 15;
#pragma unroll
  for (int n = 0; n < 4; ++n) {
    const int gcol = tn * 128 + wc * 64 + n * 16 + ccol;
    if (gcol < Nreal) {
      const float bv = bias[gcol];
#pragma unroll
      for (int m = 0; m < 4; ++m) {
#pragma unroll
        for (int j = 0; j < 4; ++j) {
          const int grow = tm * 128 + wr * 64 + m * 16 + crow + j;
          const float v = acc[m][n][j] + bv;
          if (MODE == 0) ((float*)Cout)[(size_t)grow * ldc + gcol] = v;
          else ((uint16_t*)Cout)[((size_t)(grow & 127) * 32 + (grow >> 7)) * (size_t)ldc + gcol] = f2bf(v);
        }
      }
    }
  }
}

// ---------------- persistent recurrence kernel ----------------
__device__ __forceinline__ void gbar(int* cnt, int target) {
  __syncthreads();
  if (threadIdx.x == 0) {
    __threadfence();                                                     // release my WG's writes
    __hip_atomic_fetch_add(cnt, 1, __ATOMIC_RELAXED, __HIP_MEMORY_SCOPE_AGENT);
    while (__hip_atomic_load(cnt, __ATOMIC_RELAXED, __HIP_MEMORY_SCOPE_AGENT) < target)
      __builtin_amdgcn_s_sleep(2);
  }
  __syncthreads();
  __threadfence();                                                       // acquire: drop stale cached lines
}

__global__ __launch_bounds__(256, 1) void recur_kernel(
    const uint32_t* __restrict__ memT2, const uint32_t* __restrict__ mem2,
    const uint16_t* __restrict__ Wp, const uint16_t* __restrict__ Xg,
    float* __restrict__ ctxg, float* __restrict__ h0, float* __restrict__ h1,
    float* __restrict__ cst, uint16_t* __restrict__ hA, int* __restrict__ bar) {
  __shared__ __align__(16) union {
    uint16_t chx[32 * 1024];                       // [b][k] bf16, k = [ctx(512); h(512)]
    float red[9216];                               // partial-reduce scratch (stride 35) + dots at 8960
    struct { float hl[512]; float al[256]; float r[8]; } p1;
  } U;

  const int w = blockIdx.x;
  const int tid = threadIdx.x;
  const int jr = tid & 7, kq = tid >> 3;

  // gate-weight slice pinned in registers: thread (jr,kq) holds Wp[w*8+jr][{kq*16..+16} of each 512-half]
  float wreg[32];
  {
    const uint16_t* wrow = Wp + ((size_t)(w * 8 + jr)) * 1024;
#pragma unroll
    for (int hh = 0; hh < 2; ++hh)
#pragma unroll
      for (int j = 0; j < 16; ++j)
        wreg[hh * 16 + j] = bf2f(wrow[hh * 512 + kq * 16 + j]);
  }

  int ph = 0;
  for (int t = 0; t < TT; ++t) {
    const float* hcur = (t & 1) ? h1 : h0;
    float* hnxt = (t & 1) ? h0 : h1;

    // ---- phase 1: attention (WG b = w < 32) ----
    if (w < 32) {
      const int b = w;
      U.p1.hl[tid] = hcur[b * 512 + tid];
      U.p1.hl[tid + 256] = hcur[b * 512 + tid + 256];
      __syncthreads();
      float s = 0.f;
      const uint32_t* mt = memT2 + ((size_t)b << 16) + tid;              // thread = key k
#pragma unroll 8
      for (int e2 = 0; e2 < 256; ++e2) {
        uint32_t u = mt[(size_t)e2 << 8];
        float2 hv = *(const float2*)(&U.p1.hl[e2 * 2]);
        s = fmaf(blo(u), hv.x, s);
        s = fmaf(bhi(u), hv.y, s);
      }
      s *= 0.044194173824159216f;                                        // 1/sqrt(512)
      float mx = s;
#pragma unroll
      for (int d = 32; d > 0; d >>= 1) mx = fmaxf(mx, __shfl_xor(mx, d));
      if ((tid & 63) == 0) U.p1.r[tid >> 6] = mx;
      __syncthreads();
      mx = fmaxf(fmaxf(U.p1.r[0], U.p1.r[1]), fmaxf(U.p1.r[2], U.p1.r[3]));
      float e = __expf(s - mx);
      float sm = e;
#pragma unroll
      for (int d = 32; d > 0; d >>= 1) sm += __shfl_xor(sm, d);
      if ((tid & 63) == 0) U.p1.r[4 + (tid >> 6)] = sm;
      __syncthreads();
      float tot = (U.p1.r[4] + U.p1.r[5]) + (U.p1.r[6] + U.p1.r[7]);
      U.p1.al[tid] = e / tot;
      __syncthreads();
      const uint32_t* m2 = mem2 + ((size_t)b << 16) + tid;               // thread = e2
      float cx = 0.f, cy = 0.f;
#pragma unroll 8
      for (int k = 0; k < 256; ++k) {
        uint32_t u = m2[(size_t)k << 8];
        float a = U.p1.al[k];
        cx = fmaf(blo(u), a, cx);
        cy = fmaf(bhi(u), a, cy);
      }
      ctxg[b * 512 + tid * 2] = cx;
      ctxg[b * 512 + tid * 2 + 1] = cy;
    }
    ++ph; gbar(bar, ph * NWG);

    // ---- phase 2: gates GEMV + LSTM pointwise (all 256 WGs, 8 gate rows each) ----
    {
      int k = tid * 4;                                                   // stage [ctx;h] as bf16 into LDS
      const float* src = (k < 512) ? (ctxg + k) : (hcur + (k - 512));
      for (int bi = 0; bi < 32; ++bi) {
        f32x4 v = *(const f32x4*)(src + (size_t)bi * 512);
        uint32_t* dst = (uint32_t*)&U.chx[bi * 1024 + k];
        dst[0] = (uint32_t)f2bf(v[0]) | ((uint32_t)f2bf(v[1]) << 16);
        dst[1] = (uint32_t)f2bf(v[2]) | ((uint32_t)f2bf(v[3]) << 16);
      }
    }
    __syncthreads();
    float part[32];
#pragma unroll
    for (int bi = 0; bi < 32; ++bi) part[bi] = 0.f;
#pragma unroll
    for (int hh = 0; hh < 2; ++hh) {
      const int kb = hh * 512 + kq * 16;
      for (int bi = 0; bi < 32; ++bi) {
        const uint32_t* xp = (const uint32_t*)&U.chx[bi * 1024 + kb];
        float s = part[bi];
#pragma unroll
        for (int j2 = 0; j2 < 8; ++j2) {
          uint32_t u = xp[j2];
          s = fmaf(blo(u), wreg[hh * 16 + j2 * 2], s);
          s = fmaf(bhi(u), wreg[hh * 16 + j2 * 2 + 1], s);
        }
        part[bi] = s;
      }
    }
    __syncthreads();
#pragma unroll
    for (int bi = 0; bi < 32; ++bi) U.red[(bi * 8 + jr) * 35 + kq] = part[bi];
    __syncthreads();
    {
      float s = 0.f;
      const float* rp = U.red + tid * 35;                                // output o = tid = bi*8 + jr
#pragma unroll
      for (int j = 0; j < 32; ++j) s += rp[j];
      int bi = tid >> 3, j8 = tid & 7;
      s += bf2f(Xg[((size_t)(t * 32 + bi)) * 2048 + w * 8 + j8]);        // x-part + biases (precomputed)
      U.red[8960 + tid] = s;
    }
    __syncthreads();
    if (tid < 64) {
      int bi = tid >> 1, rr = tid & 1;
      const float* dd = U.red + 8960 + bi * 8;
      float gi = dd[rr], gf = dd[2 + rr], gg = dd[4 + rr], go = dd[6 + rr];
      int r = w * 2 + rr;
      float cold = cst[bi * 512 + r];
      float cn = (1.f / (1.f + __expf(-gf))) * cold + (1.f / (1.f + __expf(-gi))) * tanhf(gg);
      float hn = (1.f / (1.f + __expf(-go))) * tanhf(cn);
      cst[bi * 512 + r] = cn;
      hnxt[bi * 512 + r] = hn;
      hA[((size_t)(bi * TT + t)) * 512 + r] = f2bf(hn);
    }
    ++ph; gbar(bar, ph * NWG);
  }
}

// ---------------- launch ----------------
extern "C" void kernel_launch(void* const* d_in, const int* in_sizes, int n_in,
                              void* d_out, int out_size, void* d_ws, size_t ws_size,
                              hipStream_t stream) {
  const float* memory = (const float*)d_in[0];
  const int*   tgt    = (const int*)d_in[1];
  const float* emb_in = (const float*)d_in[2];
  const float* W_ih   = (const float*)d_in[3];
  const float* W_hh   = (const float*)d_in[4];
  const float* b_ih   = (const float*)d_in[5];
  const float* b_hh   = (const float*)d_in[6];
  const float* W_out  = (const float*)d_in[7];
  const float* b_out  = (const float*)d_in[8];
  float* out = (float*)d_out;
  char* ws = (char*)d_ws;

  uint32_t* memT2 = (uint32_t*)(ws);                    // 8,388,608  [b][e2][k]
  uint32_t* mem2  = (uint32_t*)(ws + 8388608);          // 8,388,608  [b][k][e2]
  uint16_t* Wp    = (uint16_t*)(ws + 16777216);         // 4,194,304  [jp][1024] bf16
  uint16_t* Wxp   = (uint16_t*)(ws + 20971520);         // 2,097,152  [jp][512]  bf16
  float*    biasp = (float*)(ws + 23068672);            // 8,192
  uint16_t* WoP   = (uint16_t*)(ws + 23076864);         // 10,354,688 [10112][512] bf16 (pad rows zeroed)
  uint16_t* Axg   = (uint16_t*)(ws + 33431552);         // 4,194,304  [4096][512] bf16
  uint16_t* Xg    = (uint16_t*)(ws + 37625856);         // 16,777,216 [t*32+b][2048] bf16
  uint16_t* hA    = (uint16_t*)(ws + 54403072);         // 4,194,304  [b*128+t][512] bf16
  float*    ctxg  = (float*)(ws + 58597376);            // 65,536
  float*    h0    = (float*)(ws + 58662912);            // 65,536
  float*    h1    = (float*)(ws + 58728448);            // 65,536
  float*    cst   = (float*)(ws + 58793984);            // 65,536
  int*      bar   = (int*)(ws + 58859520);              // 256  (must be re-zeroed every call!)

  hipMemsetAsync(bar, 0, 256, stream);
  hipMemsetAsync(h0, 0, 65536, stream);
  hipMemsetAsync(cst, 0, 65536, stream);

  k_prep_mem<<<16384, 256, 0, stream>>>(memory, memT2, mem2);
  k_prep_w<<<8192, 256, 0, stream>>>(W_ih, W_hh, b_ih, b_hh, Wp, Wxp, biasp);
  k_prep_wo<<<20224, 256, 0, stream>>>(W_out, WoP);
  k_gather_x<<<8192, 256, 0, stream>>>(emb_in, tgt, Axg);

  // Xg = x_emb @ Wx^T + (b_ih+b_hh), stored [t*32+b][jp] bf16
  gemm_bt<1><<<32 * 16, 256, 0, stream>>>(Axg, Wxp, biasp, Xg, 512, 2048, 2048, 16);

  // persistent recurrence: 256 WGs, one per CU (co-resident), custom grid barrier
  recur_kernel<<<NWG, 256, 0, stream>>>(memT2, mem2, Wp, Xg, ctxg, h0, h1, cst, hA, bar);

  // logits = hA @ WoP^T + b_out  -> (B,T,V) fp32
  gemm_bt<0><<<32 * 79, 256, 0, stream>>>(hA, WoP, b_out, out, 512, 10000, 10000, 79);
}

// Round 4
// 8066.885 us; speedup vs baseline: 1.3778x; 1.3778x over previous
//
#include <hip/hip_runtime.h>
#include <stdint.h>

#define TT 128

typedef __attribute__((ext_vector_type(8))) short short8;
typedef __attribute__((ext_vector_type(4))) float f32x4;
typedef __attribute__((ext_vector_type(4))) uint32_t u32x4;

__device__ __forceinline__ float blo(uint32_t u){ union{uint32_t i; float f;} v; v.i = u << 16; return v.f; }
__device__ __forceinline__ float bhi(uint32_t u){ union{uint32_t i; float f;} v; v.i = u & 0xffff0000u; return v.f; }
__device__ __forceinline__ float bf2f(uint16_t u){ union{uint32_t i; float f;} v; v.i = ((uint32_t)u) << 16; return v.f; }
__device__ __forceinline__ uint16_t f2bf(float f){
  union{float f; uint32_t i;} v; v.f = f;
  uint32_t r = v.i + 0x7fffu + ((v.i >> 16) & 1u);
  return (uint16_t)(r >> 16);
}
__device__ __forceinline__ uint32_t bfpack(float a, float b) {
  return (uint32_t)f2bf(a) | ((uint32_t)f2bf(b) << 16);
}

// ---------------- prep kernels ----------------
// memK[b][k][e2] (scores operand) and memT[b][e2][k] (context operand), bf16x2-packed u32.
__global__ __launch_bounds__(256) void k_prep_mem(const float* __restrict__ mem,
                                                  uint32_t* __restrict__ memK,
                                                  uint32_t* __restrict__ memT) {
  int idx = blockIdx.x * 256 + threadIdx.x;   // 2 * 32*256*256
  if (idx < 2097152) {
    int e2 = idx & 255, k = (idx >> 8) & 255, b = idx >> 16;
    const float* p = mem + ((size_t)(b * 256 + k)) * 512 + e2 * 2;
    memK[idx] = bfpack(p[0], p[1]);
  } else {
    int j = idx - 2097152;
    int k = j & 255, e2 = (j >> 8) & 255, b = j >> 16;
    const float* p = mem + ((size_t)(b * 256 + k)) * 512 + e2 * 2;
    memT[j] = bfpack(p[0], p[1]);
  }
}

// Gate weights tiled for wave-contiguous streaming: W_t[jb][k8][lane][kk] u32 = bf16x2 of
// (Wfull[jb*64+lane][k8*8+kk*2], ...+1), where Wfull[j][k] = k<512 ? W_ih[j][k] : W_hh[j][k-512].
__global__ __launch_bounds__(256) void k_prep_wt(const float* __restrict__ W_ih, const float* __restrict__ W_hh,
                                                 uint32_t* __restrict__ W_t) {
  int idx = blockIdx.x * 256 + threadIdx.x;   // 1048576
  int kk = idx & 3, lane = (idx >> 2) & 63, k8 = (idx >> 8) & 127, jb = idx >> 15;
  int j = jb * 64 + lane;
  int k0 = k8 * 8 + kk * 2;
  float w0 = (k0 < 512) ? W_ih[(size_t)j * 1024 + k0] : W_hh[(size_t)j * 512 + (k0 - 512)];
  float w1 = (k0 + 1 < 512) ? W_ih[(size_t)j * 1024 + k0 + 1] : W_hh[(size_t)j * 512 + (k0 + 1 - 512)];
  W_t[idx] = bfpack(w0, w1);
}

// Wxp[j][k] bf16 (x-part of W_ih) + combined bias
__global__ __launch_bounds__(256) void k_prep_wx(const float* __restrict__ W_ih,
                                                 const float* __restrict__ b_ih, const float* __restrict__ b_hh,
                                                 uint16_t* __restrict__ Wxp, float* __restrict__ biasp) {
  int idx = blockIdx.x * 256 + threadIdx.x;   // 2048*512
  int k = idx & 511, j = idx >> 9;
  Wxp[idx] = f2bf(W_ih[(size_t)j * 1024 + 512 + k]);
  if (k == 0) biasp[j] = b_ih[j] + b_hh[j];
}

__global__ __launch_bounds__(256) void k_prep_wo(const float* __restrict__ W_out, uint16_t* __restrict__ WoP) {
  int idx = blockIdx.x * 256 + threadIdx.x;   // 10112*512 (pad rows zeroed)
  if (idx < 5120000) WoP[idx] = f2bf(W_out[idx]);
  else WoP[idx] = 0;
}

__global__ __launch_bounds__(256) void k_gather_x(const float* __restrict__ emb, const int* __restrict__ tgt,
                                                  uint16_t* __restrict__ Axg) {
  int idx = blockIdx.x * 256 + threadIdx.x;   // 4096*512, row m = b*128+t (tgt flat order)
  int k = idx & 511, m = idx >> 9;
  Axg[idx] = f2bf(emb[(size_t)tgt[m] * 512 + k]);
}

// ---------------- bf16 MFMA GEMM, C = A(MxK) * B(NxK)^T + bias ----------------
// MODE 0: fp32 out row-major. MODE 1: bf16 out row-major.
template<int MODE>
__global__ __launch_bounds__(256) void gemm_bt(const uint16_t* __restrict__ A, const uint16_t* __restrict__ B,
                                               const float* __restrict__ bias, void* __restrict__ Cout,
                                               int K, int Nreal, int ldc, int tilesN) {
  __shared__ __align__(16) uint16_t As[128 * 32];
  __shared__ __align__(16) uint16_t Bs[128 * 32];
  const int tid = threadIdx.x;
  const int wv = tid >> 6, lane = tid & 63;
  const int tm = blockIdx.x / tilesN, tn = blockIdx.x % tilesN;
  const int wr = wv >> 1, wc = wv & 1;

  f32x4 acc[4][4];
#pragma unroll
  for (int m = 0; m < 4; ++m)
#pragma unroll
    for (int n = 0; n < 4; ++n) acc[m][n] = (f32x4){0.f, 0.f, 0.f, 0.f};

  const int frow = lane & 15;
  const int fk = (lane >> 4) << 3;
  const int srow = lane >> 2;
  const int skof = (lane & 3) << 3;

  const uint16_t* Abase = A + (size_t)tm * 128 * K;
  const uint16_t* Bbase = B + (size_t)tn * 128 * K;

  for (int k0 = 0; k0 < K; k0 += 32) {
    __syncthreads();
#pragma unroll
    for (int i = 0; i < 2; ++i) {               // 8 chunks of 16 rows = 128 rows
      const int chunk = wv * 2 + i;
      const int row = chunk * 16 + srow;
      const uint16_t* ga = Abase + (size_t)row * K + k0 + skof;
      const uint16_t* gb = Bbase + (size_t)row * K + k0 + skof;
      __builtin_amdgcn_global_load_lds((const __attribute__((address_space(1))) uint32_t*)(const void*)ga,
                                       (__attribute__((address_space(3))) uint32_t*)(void*)(As + chunk * 512),
                                       16, 0, 0);
      __builtin_amdgcn_global_load_lds((const __attribute__((address_space(1))) uint32_t*)(const void*)gb,
                                       (__attribute__((address_space(3))) uint32_t*)(void*)(Bs + chunk * 512),
                                       16, 0, 0);
    }
    __syncthreads();
    short8 af[4], bfr[4];
#pragma unroll
    for (int m = 0; m < 4; ++m) af[m] = *(const short8*)(As + (wr * 64 + m * 16 + frow) * 32 + fk);
#pragma unroll
    for (int n = 0; n < 4; ++n) bfr[n] = *(const short8*)(Bs + (wc * 64 + n * 16 + frow) * 32 + fk);
#pragma unroll
    for (int m = 0; m < 4; ++m)
#pragma unroll
      for (int n = 0; n < 4; ++n)
        acc[m][n] = __builtin_amdgcn_mfma_f32_16x16x32_bf16(af[m], bfr[n], acc[m][n], 0, 0, 0);
  }

  const int crow = (lane >> 4) << 2;
  const int ccol = lane & 15;
#pragma unroll
  for (int n = 0; n < 4; ++n) {
    const int gcol = tn * 128 + wc * 64 + n * 16 + ccol;
    if (gcol < Nreal) {
      const float bv = bias[gcol];
#pragma unroll
      for (int m = 0; m < 4; ++m) {
#pragma unroll
        for (int j = 0; j < 4; ++j) {
          const int grow = tm * 128 + wr * 64 + m * 16 + crow + j;
          const float v = acc[m][n][j] + bv;
          if (MODE == 0) ((float*)Cout)[(size_t)grow * ldc + gcol] = v;
          else ((uint16_t*)Cout)[(size_t)grow * ldc + gcol] = f2bf(v);
        }
      }
    }
  }
}

// ---------------- per-batch recurrence: 32 WGs x 1024 threads, NO inter-WG sync ----------------
__global__ __launch_bounds__(1024, 1) void recur_kernel(
    const uint32_t* __restrict__ memK, const uint32_t* __restrict__ memT,
    const uint32_t* __restrict__ W_t, const uint16_t* __restrict__ Xg,
    uint16_t* __restrict__ hA) {
  __shared__ __align__(16) uint32_t hx[512];       // bf16x2 pairs: [0..256)=ctx, [256..512)=h
  __shared__ __align__(16) float s_lds[256];       // scores, then attention weights (in-place)
  __shared__ float r_lds[8];
  __shared__ __align__(16) float out_lds[2048];    // gate pre-activations

  const int b = blockIdx.x;
  const int tid = threadIdx.x;
  const int lane = tid & 63, wv = tid >> 6;
  const int kq = tid >> 2, p = tid & 3;            // scores: key=kq; context: e2=kq; part p

  const uint32_t* mK = memK + ((size_t)b << 16);
  const uint32_t* mT = memT + ((size_t)b << 16);

  if (tid < 512) hx[tid] = 0u;                     // h(0)=0 (ctx section overwritten each step)
  float c = 0.f;                                   // c[tid] for tid<512, register-resident
  __syncthreads();

  for (int t = 0; t < TT; ++t) {
    // ---- A: scores s_k = h . mem[b,k,:] ----
    {
      float s = 0.f;
      const uint32_t* kp = mK + kq * 256 + p * 64;
      const uint32_t* hp = hx + 256 + p * 64;
#pragma unroll 4
      for (int i = 0; i < 16; ++i) {
        u32x4 m4 = *(const u32x4*)(kp + i * 4);
        u32x4 h4 = *(const u32x4*)(hp + i * 4);    // LDS broadcast within lane groups
        s = fmaf(blo(m4.x), blo(h4.x), s); s = fmaf(bhi(m4.x), bhi(h4.x), s);
        s = fmaf(blo(m4.y), blo(h4.y), s); s = fmaf(bhi(m4.y), bhi(h4.y), s);
        s = fmaf(blo(m4.z), blo(h4.z), s); s = fmaf(bhi(m4.z), bhi(h4.z), s);
        s = fmaf(blo(m4.w), blo(h4.w), s); s = fmaf(bhi(m4.w), bhi(h4.w), s);
      }
      s += __shfl_xor(s, 1); s += __shfl_xor(s, 2);
      if (p == 0) s_lds[kq] = s;
    }
    __syncthreads();
    // ---- B: softmax over 256 keys ----
    float sv = 0.f, ev = 0.f;
    if (tid < 256) {
      sv = s_lds[tid] * 0.044194173824159216f;     // 1/sqrt(512)
      float mx = sv;
#pragma unroll
      for (int d = 32; d > 0; d >>= 1) mx = fmaxf(mx, __shfl_xor(mx, d));
      if (lane == 0) r_lds[wv] = mx;
    }
    __syncthreads();
    if (tid < 256) {
      float mx = fmaxf(fmaxf(r_lds[0], r_lds[1]), fmaxf(r_lds[2], r_lds[3]));
      ev = __expf(sv - mx);
      float sm = ev;
#pragma unroll
      for (int d = 32; d > 0; d >>= 1) sm += __shfl_xor(sm, d);
      if (lane == 0) r_lds[4 + wv] = sm;
    }
    __syncthreads();
    if (tid < 256) {
      float tot = (r_lds[4] + r_lds[5]) + (r_lds[6] + r_lds[7]);
      s_lds[tid] = ev / tot;                       // attention weights
    }
    __syncthreads();
    // ---- C: context ctx[2e2..2e2+1] = sum_k a_k * mem[b,k,e] ----
    {
      float cx = 0.f, cy = 0.f;
      const uint32_t* tp = mT + kq * 256 + p * 64;
      const float* ap = s_lds + p * 64;
#pragma unroll 4
      for (int i = 0; i < 16; ++i) {
        u32x4 t4 = *(const u32x4*)(tp + i * 4);
        f32x4 a4 = *(const f32x4*)(ap + i * 4);
        cx = fmaf(blo(t4.x), a4.x, cx); cy = fmaf(bhi(t4.x), a4.x, cy);
        cx = fmaf(blo(t4.y), a4.y, cx); cy = fmaf(bhi(t4.y), a4.y, cy);
        cx = fmaf(blo(t4.z), a4.z, cx); cy = fmaf(bhi(t4.z), a4.z, cy);
        cx = fmaf(blo(t4.w), a4.w, cx); cy = fmaf(bhi(t4.w), a4.w, cy);
      }
      cx += __shfl_xor(cx, 1); cx += __shfl_xor(cx, 2);
      cy += __shfl_xor(cy, 1); cy += __shfl_xor(cy, 2);
      if (p == 0) hx[kq] = bfpack(cx, cy);
    }
    __syncthreads();
    // ---- D: gates GEMV, out[j] = W[j,:] . [ctx;h] + Xg[m,j]; wave wv owns j-blocks wv and wv+16 ----
    {
      const size_t m = (size_t)b * TT + t;
      float a0 = bf2f(Xg[m * 2048 + wv * 64 + lane]);
      float a1 = bf2f(Xg[m * 2048 + (wv + 16) * 64 + lane]);
      const uint32_t* w0p = W_t + ((size_t)wv << 15) + lane * 4;
      const uint32_t* w1p = W_t + ((size_t)(wv + 16) << 15) + lane * 4;
#pragma unroll 8
      for (int k8 = 0; k8 < 128; ++k8) {
        u32x4 x4 = *(const u32x4*)(hx + k8 * 4);   // broadcast
        u32x4 wa = *(const u32x4*)(w0p + k8 * 256);
        u32x4 wb = *(const u32x4*)(w1p + k8 * 256);
        a0 = fmaf(blo(wa.x), blo(x4.x), a0); a0 = fmaf(bhi(wa.x), bhi(x4.x), a0);
        a0 = fmaf(blo(wa.y), blo(x4.y), a0); a0 = fmaf(bhi(wa.y), bhi(x4.y), a0);
        a0 = fmaf(blo(wa.z), blo(x4.z), a0); a0 = fmaf(bhi(wa.z), bhi(x4.z), a0);
        a0 = fmaf(blo(wa.w), blo(x4.w), a0); a0 = fmaf(bhi(wa.w), bhi(x4.w), a0);
        a1 = fmaf(blo(wb.x), blo(x4.x), a1); a1 = fmaf(bhi(wb.x), bhi(x4.x), a1);
        a1 = fmaf(blo(wb.y), blo(x4.y), a1); a1 = fmaf(bhi(wb.y), bhi(x4.y), a1);
        a1 = fmaf(blo(wb.z), blo(x4.z), a1); a1 = fmaf(bhi(wb.z), bhi(x4.z), a1);
        a1 = fmaf(blo(wb.w), blo(x4.w), a1); a1 = fmaf(bhi(wb.w), bhi(x4.w), a1);
      }
      out_lds[wv * 64 + lane] = a0;
      out_lds[(wv + 16) * 64 + lane] = a1;
    }
    __syncthreads();
    // ---- E: LSTM pointwise, thread r<512 owns state dim r ----
    if (tid < 512) {
      float gi = out_lds[tid], gf = out_lds[512 + tid], gg = out_lds[1024 + tid], go = out_lds[1536 + tid];
      c = (1.f / (1.f + __expf(-gf))) * c + (1.f / (1.f + __expf(-gi))) * tanhf(gg);
      float hn = (1.f / (1.f + __expf(-go))) * tanhf(c);
      float hn1 = __shfl_xor(hn, 1);
      if ((tid & 1) == 0) {
        uint32_t bp = bfpack(hn, hn1);
        hx[256 + (tid >> 1)] = bp;
        ((uint32_t*)hA)[(((size_t)b * TT + t) * 512 + tid) >> 1] = bp;
      }
    }
    __syncthreads();
  }
}

// ---------------- launch ----------------
extern "C" void kernel_launch(void* const* d_in, const int* in_sizes, int n_in,
                              void* d_out, int out_size, void* d_ws, size_t ws_size,
                              hipStream_t stream) {
  const float* memory = (const float*)d_in[0];
  const int*   tgt    = (const int*)d_in[1];
  const float* emb_in = (const float*)d_in[2];
  const float* W_ih   = (const float*)d_in[3];
  const float* W_hh   = (const float*)d_in[4];
  const float* b_ih   = (const float*)d_in[5];
  const float* b_hh   = (const float*)d_in[6];
  const float* W_out  = (const float*)d_in[7];
  const float* b_out  = (const float*)d_in[8];
  float* out = (float*)d_out;
  char* ws = (char*)d_ws;

  uint32_t* memK  = (uint32_t*)(ws);                    // 8,388,608  [b][k][e2] bf16x2
  uint32_t* memT  = (uint32_t*)(ws + 8388608);          // 8,388,608  [b][e2][k] bf16x2
  uint32_t* W_t   = (uint32_t*)(ws + 16777216);         // 4,194,304  [jb][k8][lane][4] bf16x2
  uint16_t* Wxp   = (uint16_t*)(ws + 20971520);         // 2,097,152  [j][512] bf16
  float*    biasp = (float*)(ws + 23068672);            // 8,192
  uint16_t* WoP   = (uint16_t*)(ws + 23076864);         // 10,354,688 [10112][512] bf16 (pad rows zeroed)
  uint16_t* Axg   = (uint16_t*)(ws + 33431552);         // 4,194,304  [m=b*128+t][512] bf16
  uint16_t* Xg    = (uint16_t*)(ws + 37625856);         // 16,777,216 [m][2048] bf16
  uint16_t* hA    = (uint16_t*)(ws + 54403072);         // 4,194,304  [m][512] bf16

  k_prep_mem<<<16384, 256, 0, stream>>>(memory, memK, memT);
  k_prep_wt<<<4096, 256, 0, stream>>>(W_ih, W_hh, W_t);
  k_prep_wx<<<4096, 256, 0, stream>>>(W_ih, b_ih, b_hh, Wxp, biasp);
  k_prep_wo<<<20224, 256, 0, stream>>>(W_out, WoP);
  k_gather_x<<<8192, 256, 0, stream>>>(emb_in, tgt, Axg);

  // Xg = x_emb @ Wx^T + (b_ih+b_hh), bf16 row-major [m][2048]
  gemm_bt<1><<<32 * 16, 256, 0, stream>>>(Axg, Wxp, biasp, Xg, 512, 2048, 2048, 16);

  // barrier-free per-batch recurrence
  recur_kernel<<<32, 1024, 0, stream>>>(memK, memT, W_t, Xg, hA);

  // logits = hA @ WoP^T + b_out  -> (B,T,V) fp32
  gemm_bt<0><<<32 * 79, 256, 0, stream>>>(hA, WoP, b_out, out, 512, 10000, 10000, 79);
}